// Round 1
// baseline (180.008 us; speedup 1.0000x reference)
//
#include <hip/hip_runtime.h>

// MechanicsPINN: residual = EI*biharm(f) + GC*lap(f) + KC*f - P,
// f = MLP(x) with layers 2->256->512->1024->65536, B=64, grid 256x256.
// Inputs: 0:x_coloc[64,2] 1:P[64,65536] 2:W1[2,256] 3:b1 4:W2[256,512] 5:b2
//         6:W3[512,1024] 7:b3 8:W4[1024,65536] 9:b4. All fp32. Out fp32 [64,65536].

#define BATCH 64
#define HH 256
#define WW 256
#define NPIX 65536

// ---------------- Layer 1: h1 = relu(x @ W1 + b1), K=2 ----------------
__global__ void k_l1(const float* __restrict__ x, const float* __restrict__ W1,
                     const float* __restrict__ b1, float* __restrict__ h1) {
    int gid = blockIdx.x * 256 + threadIdx.x;   // 64*256 threads
    int m = gid >> 8, n = gid & 255;
    float v = x[m * 2 + 0] * W1[n] + x[m * 2 + 1] * W1[256 + n] + b1[n];
    h1[gid] = v > 0.f ? v : 0.f;
}

// ------------- Generic small layer: out = relu(A @ W + b) -------------
// A [64][K], W [K][N]. 16x16 output tile per block, Kc=64 LDS chunks.
__global__ void k_layer(const float* __restrict__ A, const float* __restrict__ Wt,
                        const float* __restrict__ bias, float* __restrict__ out,
                        int K, int N, int do_relu) {
    __shared__ float As[16][64];
    __shared__ float Ws[64][16];
    int tid = threadIdx.x;
    int tn = tid & 15, tm = tid >> 4;
    int n0 = blockIdx.x * 16, m0 = blockIdx.y * 16;
    float acc = 0.f;
    for (int k0 = 0; k0 < K; k0 += 64) {
#pragma unroll
        for (int j = 0; j < 4; ++j) {          // stage A 16x64
            int e = j * 256 + tid;
            As[e >> 6][e & 63] = A[(m0 + (e >> 6)) * K + k0 + (e & 63)];
        }
#pragma unroll
        for (int j = 0; j < 4; ++j) {          // stage W 64x16
            int e = j * 256 + tid;
            Ws[e >> 4][e & 15] = Wt[(k0 + (e >> 4)) * N + n0 + (e & 15)];
        }
        __syncthreads();
#pragma unroll
        for (int k = 0; k < 64; ++k)
            acc += As[tm][k] * Ws[k][tn];
        __syncthreads();
    }
    acc += bias[n0 + tn];
    if (do_relu) acc = acc > 0.f ? acc : 0.f;
    out[(m0 + tm) * N + n0 + tn] = acc;
}

// ---------- Main GEMM: f = h3 @ W4 + b4  (M=64, N=65536, K=1024) ----------
// Block: 64(m) x 128(n) tile, 256 threads, thread = 8m x 4n, Kc=32.
__global__ void k_gemm4(const float* __restrict__ A, const float* __restrict__ Wt,
                        const float* __restrict__ bias, float* __restrict__ f) {
    constexpr int KC = 32;
    __shared__ float As[KC][64];    // transposed: As[k][m]
    __shared__ float Ws[KC][128];
    int tid = threadIdx.x;
    int n0 = blockIdx.x * 128;
    int tn = (tid & 31) * 4;   // 4 consecutive n
    int tm = (tid >> 5) * 8;   // 8 consecutive m
    float acc[8][4] = {};
    for (int k0 = 0; k0 < 1024; k0 += KC) {
        // stage A chunk 64x32, transposed into LDS
#pragma unroll
        for (int j = 0; j < 2; ++j) {
            int e = j * 256 + tid;             // 512 float4 groups
            int m = e >> 3, kq = e & 7;
            const float4 a4 = *reinterpret_cast<const float4*>(&A[m * 1024 + k0 + kq * 4]);
            As[kq * 4 + 0][m] = a4.x;
            As[kq * 4 + 1][m] = a4.y;
            As[kq * 4 + 2][m] = a4.z;
            As[kq * 4 + 3][m] = a4.w;
        }
        // stage W chunk 32x128
#pragma unroll
        for (int j = 0; j < 4; ++j) {
            int e = j * 256 + tid;             // 1024 float4 groups
            int k = e >> 5, c = e & 31;
            *reinterpret_cast<float4*>(&Ws[k][c * 4]) =
                *reinterpret_cast<const float4*>(&Wt[(size_t)(k0 + k) * NPIX + n0 + c * 4]);
        }
        __syncthreads();
#pragma unroll
        for (int k = 0; k < KC; ++k) {
            float4 b4 = *reinterpret_cast<float4*>(&Ws[k][tn]);
            float a[8];
            *(float4*)&a[0] = *(float4*)&As[k][tm];
            *(float4*)&a[4] = *(float4*)&As[k][tm + 4];
#pragma unroll
            for (int i = 0; i < 8; ++i) {
                acc[i][0] += a[i] * b4.x;
                acc[i][1] += a[i] * b4.y;
                acc[i][2] += a[i] * b4.z;
                acc[i][3] += a[i] * b4.w;
            }
        }
        __syncthreads();
    }
    float4 bb = *reinterpret_cast<const float4*>(&bias[n0 + tn]);
#pragma unroll
    for (int i = 0; i < 8; ++i) {
        float4 o;
        o.x = acc[i][0] + bb.x;
        o.y = acc[i][1] + bb.y;
        o.z = acc[i][2] + bb.z;
        o.w = acc[i][3] + bb.w;
        *reinterpret_cast<float4*>(&f[(size_t)(tm + i) * NPIX + n0 + tn]) = o;
    }
}

// --------------------------- Stencil ---------------------------
// residual = biharm + lap + f - P, reflect-1 padding applied to f for lap
// and to lap for biharm (index reflection only; lap always at valid coords).
#define ROWS 16
__device__ __forceinline__ int rfl(int i) {
    return i < 0 ? -i : (i > 255 ? 510 - i : i);
}
__global__ void k_stencil(const float* __restrict__ f, const float* __restrict__ P,
                          float* __restrict__ out) {
    __shared__ float fs[ROWS + 4][256];
    int x = threadIdx.x;
    int y0 = blockIdx.x * ROWS;
    int b = blockIdx.y;
    const float* fb = f + (size_t)b * NPIX;
    // load rows y0-2 .. y0+ROWS+1 with reflection; slot t holds f[rfl(y0-2+t)]
    for (int t = 0; t < ROWS + 4; ++t) {
        int gy = rfl(y0 - 2 + t);
        fs[t][x] = fb[gy * 256 + x];
    }
    __syncthreads();

    int xm = x == 0 ? 1 : x - 1;
    int xp = x == 255 ? 254 : x + 1;

    auto lapAt = [&](int j, int i) {   // j,i valid coords; slot = j - y0 + 2
        int s = j - y0 + 2;
        int sm = rfl(j - 1) - y0 + 2;
        int sp = rfl(j + 1) - y0 + 2;
        int im = i == 0 ? 1 : i - 1;
        int ip = i == 255 ? 254 : i + 1;
        float c = fs[s][i];
        return (fs[sm][i] - 2.f * c + fs[sp][i]) + (fs[s][im] - 2.f * c + fs[s][ip]);
    };

    for (int r = 0; r < ROWS; ++r) {
        int y = y0 + r;
        int ym = rfl(y - 1), yp = rfl(y + 1);
        float lc = lapAt(y, x);
        float lym = lapAt(ym, x);
        float lyp = lapAt(yp, x);
        float lxm = lapAt(y, xm);
        float lxp = lapAt(y, xp);
        float bih = (lym - 2.f * lc + lyp) + (lxm - 2.f * lc + lxp);
        float fc = fs[r + 2][x];
        size_t idx = (size_t)b * NPIX + y * 256 + x;
        out[idx] = bih + lc + fc - P[idx];
    }
}

extern "C" void kernel_launch(void* const* d_in, const int* in_sizes, int n_in,
                              void* d_out, int out_size, void* d_ws, size_t ws_size,
                              hipStream_t stream) {
    const float* x  = (const float*)d_in[0];
    const float* P  = (const float*)d_in[1];
    const float* W1 = (const float*)d_in[2];
    const float* b1 = (const float*)d_in[3];
    const float* W2 = (const float*)d_in[4];
    const float* b2 = (const float*)d_in[5];
    const float* W3 = (const float*)d_in[6];
    const float* b3 = (const float*)d_in[7];
    const float* W4 = (const float*)d_in[8];
    const float* b4 = (const float*)d_in[9];
    float* out = (float*)d_out;

    char* ws = (char*)d_ws;
    float* h1 = (float*)(ws);                       // 64*256  = 64 KB
    float* h2 = (float*)(ws + (64 << 10));          // 64*512  = 128 KB
    float* h3 = (float*)(ws + (192 << 10));         // 64*1024 = 256 KB
    float* f  = (float*)(ws + (512 << 10));         // 64*65536 = 16 MB

    k_l1<<<64, 256, 0, stream>>>(x, W1, b1, h1);
    k_layer<<<dim3(512 / 16, 4), 256, 0, stream>>>(h1, W2, b2, h2, 256, 512, 1);
    k_layer<<<dim3(1024 / 16, 4), 256, 0, stream>>>(h2, W3, b3, h3, 512, 1024, 1);
    k_gemm4<<<NPIX / 128, 256, 0, stream>>>(h3, W4, b4, f);
    k_stencil<<<dim3(HH / ROWS, BATCH), 256, 0, stream>>>(f, P, out);
}

// Round 2
// 99.918 us; speedup vs baseline: 1.8016x; 1.8016x over previous
//
#include <hip/hip_runtime.h>

// MechanicsPINN: residual = EI*biharm(f) + GC*lap(f) + KC*f - P,
// f = MLP(x) 2->256->512->1024->65536, B=64, grid 256x256. All inputs fp32.
// Round 2: main GEMM (M=64,N=65536,K=1024) via bf16 MFMA, memory-bound on
// the one-shot 256MB read of W4 (fp32), converted to bf16 on the fly.

#define BATCH 64
#define NPIX 65536

typedef __attribute__((ext_vector_type(8))) short short8_t;  // bf16 x8 (4 VGPR)
typedef __attribute__((ext_vector_type(4))) float f32x4;

__device__ __forceinline__ short f2bf(float x) {  // fp32 -> bf16 RNE
    unsigned u = __float_as_uint(x);
    unsigned r = (u + 0x7fffu + ((u >> 16) & 1u)) >> 16;
    return (short)r;
}

// ---------------- Layer 1: h1 = relu(x @ W1 + b1), K=2 ----------------
__global__ void k_l1(const float* __restrict__ x, const float* __restrict__ W1,
                     const float* __restrict__ b1, float* __restrict__ h1) {
    int gid = blockIdx.x * 256 + threadIdx.x;   // 64*256 threads
    int m = gid >> 8, n = gid & 255;
    float v = x[m * 2 + 0] * W1[n] + x[m * 2 + 1] * W1[256 + n] + b1[n];
    h1[gid] = v > 0.f ? v : 0.f;
}

// ------------- Generic small layer: out = relu(A @ W + b) -------------
// A [64][K], W [K][N]. 16x16 output tile per block. If out_bf != null,
// writes bf16 ONLY (used for h3, consumed by the MFMA GEMM).
__global__ void k_layer(const float* __restrict__ A, const float* __restrict__ Wt,
                        const float* __restrict__ bias, float* __restrict__ out,
                        short* __restrict__ out_bf, int K, int N) {
    __shared__ float As[16][64];
    __shared__ float Ws[64][16];
    int tid = threadIdx.x;
    int tn = tid & 15, tm = tid >> 4;
    int n0 = blockIdx.x * 16, m0 = blockIdx.y * 16;
    float acc = 0.f;
    for (int k0 = 0; k0 < K; k0 += 64) {
#pragma unroll
        for (int j = 0; j < 4; ++j) {          // stage A 16x64
            int e = j * 256 + tid;
            As[e >> 6][e & 63] = A[(m0 + (e >> 6)) * K + k0 + (e & 63)];
        }
#pragma unroll
        for (int j = 0; j < 4; ++j) {          // stage W 64x16
            int e = j * 256 + tid;
            Ws[e >> 4][e & 15] = Wt[(k0 + (e >> 4)) * N + n0 + (e & 15)];
        }
        __syncthreads();
#pragma unroll
        for (int k = 0; k < 64; ++k)
            acc += As[tm][k] * Ws[k][tn];
        __syncthreads();
    }
    acc += bias[n0 + tn];
    acc = acc > 0.f ? acc : 0.f;               // relu (all users of this path)
    if (out_bf)
        out_bf[(m0 + tm) * N + n0 + tn] = f2bf(acc);
    else
        out[(m0 + tm) * N + n0 + tn] = acc;
}

// ---------- Main GEMM: f = h3b @ W4 + b4 (bf16 MFMA, M=64,N=65536,K=1024) ----
// Block: 512 threads (8 waves), N-chunk = 128 cols, full M=64, grid = 512.
// Wave w: m-tile (w&3)*16, n-half (w>>2)*64 -> 4 MFMA 16x16x32 per K-step.
// W staged fp32 into LDS (double-buffered 2x16KB) via global_load_lds x16B;
// converted to bf16 in-register at fragment read. A (bf16) read from global.
__global__ __launch_bounds__(512, 4) void k_gemm_mfma(
        const short* __restrict__ A,     // h3 bf16 [64][1024]
        const float* __restrict__ W,     // W4 fp32 [1024][65536]
        const float* __restrict__ bias,  // [65536]
        float* __restrict__ f) {         // [64][65536]
    __shared__ float Wl[2][32 * 128];    // [buf][k][n] fp32, 16KB each
    const int tid = threadIdx.x;
    const int lane = tid & 63;
    const int w = tid >> 6;
    const int n0 = blockIdx.x * 128;
    const int mt = (w & 3) * 16;
    const int nh = (w >> 2) * 64;
    const int lr = lane & 15;            // row/col within fragment
    const int g = lane >> 4;             // k-group 0..3

    f32x4 acc[4] = {{0.f, 0.f, 0.f, 0.f}, {0.f, 0.f, 0.f, 0.f},
                    {0.f, 0.f, 0.f, 0.f}, {0.f, 0.f, 0.f, 0.f}};

    // A-frag base: row m = mt + lr, k = g*8 (+ 32 per step), 16B contiguous
    const short* aptr = A + (mt + lr) * 1024 + g * 8;

    // staging: 1024 16B-chunks per step; thread covers chunks c=(i*8+w)*64+lane
    // LDS dest is wave-uniform base (+ lane*16 by HW); global src is per-lane.
    auto stage = [&](int buf, int k0) {
#pragma unroll
        for (int i = 0; i < 2; ++i) {
            int c = (i * 8 + w) * 64 + lane;
            const float* src = W + (size_t)(k0 + (c >> 5)) * NPIX + n0 + (c & 31) * 4;
            __builtin_amdgcn_global_load_lds(
                (const __attribute__((address_space(1))) void*)src,
                (__attribute__((address_space(3))) void*)((char*)(&Wl[buf][0]) + (i * 8 + w) * 1024),
                16, 0, 0);
        }
    };

    stage(0, 0);
    asm volatile("s_waitcnt vmcnt(0)" ::: "memory");
    __syncthreads();

    for (int s = 0; s < 32; ++s) {
        int cur = s & 1;
        if (s < 31) stage(cur ^ 1, (s + 1) * 32);

        short8_t af = *(const short8_t*)(aptr + s * 32);
        const float* wb = &Wl[cur][0];
#pragma unroll
        for (int nt = 0; nt < 4; ++nt) {
            int col = nh + nt * 16 + lr;
            short8_t bf;
#pragma unroll
            for (int j = 0; j < 8; ++j)
                bf[j] = f2bf(wb[(g * 8 + j) * 128 + col]);
            acc[nt] = __builtin_amdgcn_mfma_f32_16x16x32_bf16(af, bf, acc[nt], 0, 0, 0);
        }
        asm volatile("s_waitcnt vmcnt(0)" ::: "memory");
        __syncthreads();
    }

    // C/D layout: col = lane&15, row = (lane>>4)*4 + reg
#pragma unroll
    for (int nt = 0; nt < 4; ++nt) {
        int col = n0 + nh + nt * 16 + lr;
        float bb = bias[col];
        int rowb = mt + g * 4;
#pragma unroll
        for (int r = 0; r < 4; ++r)
            f[(size_t)(rowb + r) * NPIX + col] = acc[nt][r] + bb;
    }
}

// --------------------------- Stencil ---------------------------
// residual = biharm + lap + f - P; reflect-1 index reflection.
#define ROWS 16
__device__ __forceinline__ int rfl(int i) {
    return i < 0 ? -i : (i > 255 ? 510 - i : i);
}
__global__ void k_stencil(const float* __restrict__ f, const float* __restrict__ P,
                          float* __restrict__ out) {
    __shared__ float fs[ROWS + 4][256];
    int x = threadIdx.x;
    int y0 = blockIdx.x * ROWS;
    int b = blockIdx.y;
    const float* fb = f + (size_t)b * NPIX;
    for (int t = 0; t < ROWS + 4; ++t) {
        int gy = rfl(y0 - 2 + t);
        fs[t][x] = fb[gy * 256 + x];
    }
    __syncthreads();

    int xm = x == 0 ? 1 : x - 1;
    int xp = x == 255 ? 254 : x + 1;

    auto lapAt = [&](int j, int i) {
        int s = j - y0 + 2;
        int sm = rfl(j - 1) - y0 + 2;
        int sp = rfl(j + 1) - y0 + 2;
        int im = i == 0 ? 1 : i - 1;
        int ip = i == 255 ? 254 : i + 1;
        float c = fs[s][i];
        return (fs[sm][i] - 2.f * c + fs[sp][i]) + (fs[s][im] - 2.f * c + fs[s][ip]);
    };

    for (int r = 0; r < ROWS; ++r) {
        int y = y0 + r;
        float lc = lapAt(y, x);
        float lym = lapAt(rfl(y - 1), x);
        float lyp = lapAt(rfl(y + 1), x);
        float lxm = lapAt(y, xm);
        float lxp = lapAt(y, xp);
        float bih = (lym - 2.f * lc + lyp) + (lxm - 2.f * lc + lxp);
        float fc = fs[r + 2][x];
        size_t idx = (size_t)b * NPIX + y * 256 + x;
        out[idx] = bih + lc + fc - P[idx];
    }
}

extern "C" void kernel_launch(void* const* d_in, const int* in_sizes, int n_in,
                              void* d_out, int out_size, void* d_ws, size_t ws_size,
                              hipStream_t stream) {
    const float* x  = (const float*)d_in[0];
    const float* P  = (const float*)d_in[1];
    const float* W1 = (const float*)d_in[2];
    const float* b1 = (const float*)d_in[3];
    const float* W2 = (const float*)d_in[4];
    const float* b2 = (const float*)d_in[5];
    const float* W3 = (const float*)d_in[6];
    const float* b3 = (const float*)d_in[7];
    const float* W4 = (const float*)d_in[8];
    const float* b4 = (const float*)d_in[9];
    float* out = (float*)d_out;

    char* ws = (char*)d_ws;
    float* h1  = (float*)(ws);                      // 64*256*4  = 64 KB
    float* h2  = (float*)(ws + (64 << 10));         // 64*512*4  = 128 KB
    short* h3b = (short*)(ws + (192 << 10));        // 64*1024*2 = 128 KB (bf16)
    float* f   = (float*)(ws + (320 << 10));        // 64*65536*4 = 16 MB

    k_l1<<<64, 256, 0, stream>>>(x, W1, b1, h1);
    k_layer<<<dim3(512 / 16, 4), 256, 0, stream>>>(h1, W2, b2, h2, nullptr, 256, 512);
    k_layer<<<dim3(1024 / 16, 4), 256, 0, stream>>>(h2, W3, b3, nullptr, h3b, 512, 1024);
    k_gemm_mfma<<<NPIX / 128, 512, 0, stream>>>(h3b, W4, b4, f);
    k_stencil<<<dim3(256 / ROWS, BATCH), 256, 0, stream>>>(f, P, out);
}